// Round 2
// baseline (2796.776 us; speedup 1.0000x reference)
//
#include <hip/hip_runtime.h>

#define NSEQ 1028
#define TT   256
#define CC   64
#define HH   256
#define NKT  10               // k-tiles of 32 (8 for W_hh, 2 for W_ih)
#define KT_REG 4              // kt0..3 in registers
#define AROWB 656             // bytes per A row: 320*2 + 16 pad
#define SLAB  65536           // one kt slab: 8 waves * 8 ct * 512 elems * 2B
#define LSTM_LDS (2*16*AROWB + 2*SLAB)   // 20992 + 131072 = 152064
#define OUTP_LDS (128*264*2 + 64*264*2)  // 101376

typedef unsigned short u16;
typedef float  f32x4 __attribute__((ext_vector_type(4)));
typedef __bf16 v8bf  __attribute__((ext_vector_type(8)));

__device__ __forceinline__ u16 f2bf(float f){
  unsigned u = __builtin_bit_cast(unsigned, f);
  u += 0x7FFFu + ((u >> 16) & 1u);
  return (u16)(u >> 16);
}
__device__ __forceinline__ float sigm(float x){ return 1.0f/(1.0f+__expf(-x)); }
__device__ __forceinline__ float tanh_f(float x){
  float e = __expf(-2.0f*fabsf(x));
  float r = (1.0f-e)/(1.0f+e);
  return copysignf(r, x);
}
// A-tile address: rotate 16B slots within each 128B span by (row&7) -> uniform banks
__device__ __forceinline__ int a_off(int row, int b){
  int rot = (row & 7) << 4;
  return row*AROWB + ((b & ~127) | ((b + rot) & 127));
}

// ---- pack W = [W_hh | W_ih] into per-(kt,wave,ct) MFMA B-frags, bf16, 8-wave layout
__global__ void k_pack_w(const float* __restrict__ Whh, const float* __restrict__ Wih,
                         u16* __restrict__ wpack){
  int idx = blockIdx.x*256 + threadIdx.x;
  if (idx >= NKT*8*8*512) return;                 // 327680
  int j    = idx & 7;
  int lane = (idx >> 3) & 63;
  int ct   = (idx >> 9) & 7;
  int w    = (idx >> 12) & 7;
  int kt   = idx >> 15;
  int col  = (ct >> 1)*256 + w*32 + (ct & 1)*16 + (lane & 15);
  int k    = kt*32 + (lane >> 4)*8 + j;
  float v  = (k < 256) ? Whh[col*256 + k] : Wih[col*64 + (k - 256)];
  wpack[idx] = f2bf(v);
}

__global__ void k_bias(const float* __restrict__ bi, const float* __restrict__ bh,
                       float* __restrict__ bias){
  int i = blockIdx.x*256 + threadIdx.x;
  if (i < 1024) bias[i] = bi[i] + bh[i];
}

__global__ void k_wlin(const float* __restrict__ Wl, u16* __restrict__ wlin){
  int i = blockIdx.x*256 + threadIdx.x;
  if (i >= 64*264) return;
  int col = i / 264, k = i % 264;
  wlin[i] = (k < 256) ? f2bf(Wl[col*256 + k]) : (u16)0;
}

// ---- x(B,C,F,T) -> y(n,t,c) bf16, n = b*257+f
__global__ void k_ytrans(const float* __restrict__ x, u16* __restrict__ ybuf){
  __shared__ u16 tile[64][257];
  int n = blockIdx.x, b = n / 257, f = n % 257, tid = threadIdx.x;
  for (int i = tid; i < 64*256; i += 256){
    int c = i >> 8, t = i & 255;
    tile[c][t] = f2bf(x[((size_t)(b*64 + c)*257 + f)*256 + t]);
  }
  __syncthreads();
  for (int i = tid; i < 256*64; i += 256){
    int t = i >> 6, c = i & 63;
    ybuf[((size_t)n*256 + t)*64 + c] = tile[c][t];
  }
}

// ---- persistent LSTM: 65 blocks x 512 thr (8 waves), 16 seqs/block
// Residency: kt0..3 in VGPR (128/wave), kt4,5 in LDS, kt6..9 streamed from L2.
__global__ __launch_bounds__(512, 2) void k_lstm(const u16* __restrict__ wpack,
      const float* __restrict__ bias, const u16* __restrict__ ybuf,
      u16* __restrict__ hbuf){
  extern __shared__ char smem[];
  char* lA = smem;                              // [2][16 rows][AROWB]
  u16*  lW = (u16*)(smem + 2*16*AROWB);         // kt4,5 slabs
  const int tid = threadIdx.x, lane = tid & 63, w = tid >> 6;   // w 0..7
  const int n0 = blockIdx.x * 16;
  const int l15 = lane & 15, q = lane >> 4;
  const int rrow = tid >> 5, rchunk = tid & 31; // h-writeout roles (16 rows x 32 chunks)
  const int yrow = tid >> 5, ypair = tid & 31;  // y staging roles (16 seqs x 32 ch-pairs)

  // register-resident W (kt0..3): 128 VGPR
  v8bf wreg[KT_REG][8];
  #pragma unroll
  for (int kt = 0; kt < KT_REG; ++kt)
    #pragma unroll
    for (int ct = 0; ct < 8; ++ct)
      wreg[kt][ct] = *(const v8bf*)(wpack + ((kt*8 + w)*8 + ct)*512 + lane*8);

  // LDS-resident W (kt4,5)
  {
    const uint4* src = (const uint4*)(wpack + KT_REG*8*8*512);
    uint4* dst = (uint4*)lW;
    for (int i = tid; i < (2*SLAB/2)/8; i += 512) dst[i] = src[i];
  }
  float biasr[8];
  #pragma unroll
  for (int ct = 0; ct < 8; ++ct)
    biasr[ct] = bias[(ct >> 1)*256 + w*32 + (ct & 1)*16 + l15];

  { // zero both A buffers (h(-1)=0)
    unsigned* z = (unsigned*)lA;
    for (int i = tid; i < (2*16*AROWB)/4; i += 512) z[i] = 0;
  }
  __syncthreads();
  { // stage y[t=0] into buf0 (swizzled)
    unsigned v = 0;
    if (n0 + yrow < NSEQ)
      v = *(const unsigned*)(ybuf + ((size_t)(n0 + yrow)*TT + 0)*64 + ypair*2);
    *(unsigned*)(lA + a_off(yrow, 512 + ypair*4)) = v;
  }
  f32x4 creg[2];
  creg[0] = (f32x4){0.f,0.f,0.f,0.f};
  creg[1] = (f32x4){0.f,0.f,0.f,0.f};
  __syncthreads();

  for (int t = 0; t < TT; ++t){
    char* Acur = lA + (t & 1)*16*AROWB;
    char* Anxt = lA + ((t + 1) & 1)*16*AROWB;

    // issue stream kt6 early (consumed ~30 MFMAs later)
    v8bf sbuf[8];
    #pragma unroll
    for (int ct = 0; ct < 8; ++ct)
      sbuf[ct] = *(const v8bf*)(wpack + ((6*8 + w)*8 + ct)*512 + lane*8);

    // y prefetch for t+1
    unsigned yv = 0;
    if (t + 1 < TT && n0 + yrow < NSEQ)
      yv = *(const unsigned*)(ybuf + ((size_t)(n0 + yrow)*TT + (t + 1))*64 + ypair*2);

    // h(t-1) writeout (overlaps MFMA)
    if (t >= 1 && n0 + rrow < NSEQ){
      uint4 hv = *(const uint4*)(Acur + a_off(rrow, rchunk*16));
      *(uint4*)(hbuf + ((size_t)(n0 + rrow)*TT + (t - 1))*HH + rchunk*8) = hv;
    }

    f32x4 acc[8];
    #pragma unroll
    for (int ct = 0; ct < 8; ++ct)
      acc[ct] = (f32x4){biasr[ct], biasr[ct], biasr[ct], biasr[ct]};

    // kt0..3: register weights
    #pragma unroll
    for (int kt = 0; kt < KT_REG; ++kt){
      v8bf a = *(const v8bf*)(Acur + a_off(l15, kt*64 + q*16));
      #pragma unroll
      for (int ct = 0; ct < 8; ++ct)
        acc[ct] = __builtin_amdgcn_mfma_f32_16x16x32_bf16(a, wreg[kt][ct], acc[ct], 0, 0, 0);
    }
    // kt4,5: LDS weights
    #pragma unroll
    for (int kt = 4; kt < 6; ++kt){
      v8bf a = *(const v8bf*)(Acur + a_off(l15, kt*64 + q*16));
      #pragma unroll
      for (int ct = 0; ct < 8; ++ct){
        v8bf b = *(const v8bf*)(lW + (((kt - 4)*8 + w)*8 + ct)*512 + lane*8);
        acc[ct] = __builtin_amdgcn_mfma_f32_16x16x32_bf16(a, b, acc[ct], 0, 0, 0);
      }
    }
    // kt6..9: streamed, consume then reissue next
    #pragma unroll
    for (int kt = 6; kt < 10; ++kt){
      v8bf a = *(const v8bf*)(Acur + a_off(l15, kt*64 + q*16));
      #pragma unroll
      for (int ct = 0; ct < 8; ++ct)
        acc[ct] = __builtin_amdgcn_mfma_f32_16x16x32_bf16(a, sbuf[ct], acc[ct], 0, 0, 0);
      if (kt < 9){
        #pragma unroll
        for (int ct = 0; ct < 8; ++ct)
          sbuf[ct] = *(const v8bf*)(wpack + (((kt + 1)*8 + w)*8 + ct)*512 + lane*8);
      }
    }

    // elementwise cell update: lane owns units w*32+u*16+l15, seqs 4q+j
    #pragma unroll
    for (int u = 0; u < 2; ++u){
      #pragma unroll
      for (int j = 0; j < 4; ++j){
        float xi = acc[0 + u][j], xf = acc[2 + u][j], xg = acc[4 + u][j], xo = acc[6 + u][j];
        float cv = sigm(xf)*creg[u][j] + sigm(xi)*tanh_f(xg);
        float hv = sigm(xo)*tanh_f(cv);
        creg[u][j] = cv;
        int row = 4*q + j, unit = w*32 + u*16 + l15;
        *(u16*)(Anxt + a_off(row, unit*2)) = f2bf(hv);
      }
    }
    // stage y[t+1]
    if (t + 1 < TT)
      *(unsigned*)(Anxt + a_off(yrow, 512 + ypair*4)) = yv;
    __syncthreads();
  }
  { // final h[255] sits in buf (TT&1)=0
    char* Afin = lA + (TT & 1)*16*AROWB;
    if (n0 + rrow < NSEQ){
      uint4 hv = *(const uint4*)(Afin + a_off(rrow, rchunk*16));
      *(uint4*)(hbuf + ((size_t)(n0 + rrow)*TT + (TT - 1))*HH + rchunk*8) = hv;
    }
  }
}

// ---- out = h @ W_lin^T + b_lin, written as (B,OUT,F,T)
__global__ __launch_bounds__(256) void k_outproj(const u16* __restrict__ hbuf,
      const u16* __restrict__ wlin, const float* __restrict__ blin,
      float* __restrict__ out){
  extern __shared__ char smem[];
  u16* sA = (u16*)smem;                 // [128][264] rows = t
  u16* sB = (u16*)(smem + 128*264*2);   // [64][264]  rows = o
  const int n = blockIdx.x, th = blockIdx.y, t0 = th*128;
  const int b = n / 257, f = n % 257;
  const int tid = threadIdx.x, lane = tid & 63, wv = tid >> 6;

  for (int i = tid; i < 128*32; i += 256){
    int r = i >> 5, part = i & 31;
    *(uint4*)(sA + r*264 + part*8) =
        *(const uint4*)(hbuf + ((size_t)n*TT + t0 + r)*HH + part*8);
  }
  for (int i = tid; i < (64*264)/2; i += 256)
    ((unsigned*)sB)[i] = ((const unsigned*)wlin)[i];
  __syncthreads();

  f32x4 acc[2][4];
  #pragma unroll
  for (int m = 0; m < 2; ++m)
    #pragma unroll
    for (int nt = 0; nt < 4; ++nt){
      float bv = blin[nt*16 + (lane & 15)];
      acc[m][nt] = (f32x4){bv, bv, bv, bv};
    }
  const int khi = (lane >> 4) * 8;
  #pragma unroll
  for (int kt = 0; kt < 8; ++kt){
    v8bf av[2];
    #pragma unroll
    for (int m = 0; m < 2; ++m){
      int mt = wv*2 + m;
      av[m] = *(const v8bf*)(sA + (mt*16 + (lane & 15))*264 + kt*32 + khi);
    }
    #pragma unroll
    for (int nt = 0; nt < 4; ++nt){
      v8bf bv = *(const v8bf*)(sB + (nt*16 + (lane & 15))*264 + kt*32 + khi);
      #pragma unroll
      for (int m = 0; m < 2; ++m)
        acc[m][nt] = __builtin_amdgcn_mfma_f32_16x16x32_bf16(av[m], bv, acc[m][nt], 0, 0, 0);
    }
  }
  #pragma unroll
  for (int m = 0; m < 2; ++m){
    int mt = wv*2 + m;
    #pragma unroll
    for (int nt = 0; nt < 4; ++nt){
      int o = nt*16 + (lane & 15);
      int tb = t0 + mt*16 + 4*(lane >> 4);
      *(f32x4*)(out + (((size_t)b*64 + o)*257 + f)*TT + tb) = acc[m][nt];
    }
  }
}

extern "C" void kernel_launch(void* const* d_in, const int* in_sizes, int n_in,
                              void* d_out, int out_size, void* d_ws, size_t ws_size,
                              hipStream_t stream) {
  const float* x   = (const float*)d_in[0];
  const float* Wih = (const float*)d_in[1];
  const float* Whh = (const float*)d_in[2];
  const float* bih = (const float*)d_in[3];
  const float* bhh = (const float*)d_in[4];
  const float* Wl  = (const float*)d_in[5];
  const float* bl  = (const float*)d_in[6];
  float* out = (float*)d_out;

  char* p = (char*)d_ws;
  u16*   wpack = (u16*)p;   p += 655360;                 // 10 slabs
  float* bias  = (float*)p; p += 4096;
  u16*   wlin  = (u16*)p;   p += 33792;
  u16*   ybuf  = (u16*)p;   p += (size_t)NSEQ*TT*CC*2;   // 33.7 MB
  u16*   hbuf  = (u16*)p;                                // 134.7 MB

  hipFuncSetAttribute((const void*)k_lstm,    hipFuncAttributeMaxDynamicSharedMemorySize, LSTM_LDS);
  hipFuncSetAttribute((const void*)k_outproj, hipFuncAttributeMaxDynamicSharedMemorySize, OUTP_LDS);

  k_pack_w <<<1280, 256, 0, stream>>>(Whh, Wih, wpack);
  k_bias   <<<4,    256, 0, stream>>>(bih, bhh, bias);
  k_wlin   <<<66,   256, 0, stream>>>(Wl, wlin);
  k_ytrans <<<1028, 256, 0, stream>>>(x, ybuf);
  k_lstm   <<<65, 512, LSTM_LDS, stream>>>(wpack, bias, ybuf, hbuf);
  k_outproj<<<dim3(1028, 2), 256, OUTP_LDS, stream>>>(hbuf, wlin, bl, out);
}

// Round 3
// 2251.971 us; speedup vs baseline: 1.2419x; 1.2419x over previous
//
#include <hip/hip_runtime.h>

#define NSEQ 1028
#define TT   256
#define CC   64
#define HH   256
#define NKT  10               // k-tiles of 32 (8 for W_hh, 2 for W_ih)
#define AROWB 656             // bytes per A row: 320*2 + 16 pad
#define SLABE 32768           // elems per kt slab: 8 waves * 8 ct * 512
#define LSTM_LDS (2*16*AROWB + 2*SLABE*2)   // 20992 + 131072 = 152064
#define OUTP_LDS (128*264*2 + 64*264*2)     // 101376

typedef unsigned short u16;
typedef float  f32x4 __attribute__((ext_vector_type(4)));
typedef __bf16 v8bf  __attribute__((ext_vector_type(8)));

__device__ __forceinline__ u16 f2bf(float f){
  unsigned u = __builtin_bit_cast(unsigned, f);
  u += 0x7FFFu + ((u >> 16) & 1u);
  return (u16)(u >> 16);
}
__device__ __forceinline__ float sigm(float x){ return 1.0f/(1.0f+__expf(-x)); }
__device__ __forceinline__ float tanh_f(float x){
  float e = __expf(-2.0f*fabsf(x));
  float r = (1.0f-e)/(1.0f+e);
  return copysignf(r, x);
}
// A-tile address: rotate 16B slots within each 128B span by (row&7) -> uniform banks
__device__ __forceinline__ int a_off(int row, int b){
  int rot = (row & 7) << 4;
  return row*AROWB + ((b & ~127) | ((b + rot) & 127));
}
// MFMA with B pinned in AGPR (forces weight residency in the accumulator file)
__device__ __forceinline__ void mfma_a(f32x4& d, v8bf a, v8bf b){
  asm("v_mfma_f32_16x16x32_bf16 %0, %1, %2, %0" : "+v"(d) : "v"(a), "a"(b));
}
// MFMA with B in VGPR (LDS-sourced tiles); acc kept in "v" class uniformly
__device__ __forceinline__ void mfma_v(f32x4& d, v8bf a, v8bf b){
  asm("v_mfma_f32_16x16x32_bf16 %0, %1, %2, %0" : "+v"(d) : "v"(a), "v"(b));
}

// ---- pack W = [W_hh | W_ih] into per-(kt,wave,ct) MFMA B-frags, bf16, 8-wave layout
__global__ void k_pack_w(const float* __restrict__ Whh, const float* __restrict__ Wih,
                         u16* __restrict__ wpack){
  int idx = blockIdx.x*256 + threadIdx.x;
  if (idx >= NKT*SLABE) return;                 // 327680
  int j    = idx & 7;
  int lane = (idx >> 3) & 63;
  int ct   = (idx >> 9) & 7;
  int w    = (idx >> 12) & 7;
  int kt   = idx >> 15;
  int col  = (ct >> 1)*256 + w*32 + (ct & 1)*16 + (lane & 15);
  int k    = kt*32 + (lane >> 4)*8 + j;
  float v  = (k < 256) ? Whh[col*256 + k] : Wih[col*64 + (k - 256)];
  wpack[idx] = f2bf(v);
}

__global__ void k_bias(const float* __restrict__ bi, const float* __restrict__ bh,
                       float* __restrict__ bias){
  int i = blockIdx.x*256 + threadIdx.x;
  if (i < 1024) bias[i] = bi[i] + bh[i];
}

__global__ void k_wlin(const float* __restrict__ Wl, u16* __restrict__ wlin){
  int i = blockIdx.x*256 + threadIdx.x;
  if (i >= 64*264) return;
  int col = i / 264, k = i % 264;
  wlin[i] = (k < 256) ? f2bf(Wl[col*256 + k]) : (u16)0;
}

// ---- x(B,C,F,T) -> y(n,t,c) bf16, n = b*257+f
__global__ void k_ytrans(const float* __restrict__ x, u16* __restrict__ ybuf){
  __shared__ u16 tile[64][257];
  int n = blockIdx.x, b = n / 257, f = n % 257, tid = threadIdx.x;
  for (int i = tid; i < 64*256; i += 256){
    int c = i >> 8, t = i & 255;
    tile[c][t] = f2bf(x[((size_t)(b*64 + c)*257 + f)*256 + t]);
  }
  __syncthreads();
  for (int i = tid; i < 256*64; i += 256){
    int t = i >> 6, c = i & 63;
    ybuf[((size_t)n*256 + t)*64 + c] = tile[c][t];
  }
}

// ---- persistent LSTM: 65 blocks x 512 thr (8 waves), 16 seqs/block
// Residency: kt0..2 in AGPR (96/wave), kt3,4 in LDS, kt5..9 streamed from L2
// via 2-deep rolling AGPR buffers (LICM defeated with opaque pointer).
__global__ __launch_bounds__(512, 2) void k_lstm(const u16* __restrict__ wpack,
      const float* __restrict__ bias, const u16* __restrict__ ybuf,
      u16* __restrict__ hbuf){
  extern __shared__ char smem[];
  char* lA = smem;                              // [2][16 rows][AROWB]
  u16*  lW = (u16*)(smem + 2*16*AROWB);         // kt3,4 slabs
  const int tid = threadIdx.x, lane = tid & 63, w = tid >> 6;   // w 0..7
  const int n0 = blockIdx.x * 16;
  const int l15 = lane & 15, q = lane >> 4;
  const int rrow = tid >> 5, rchunk = tid & 31; // h-writeout roles
  const int yrow = tid >> 5, ypair = tid & 31;  // y staging roles

  // AGPR-resident W (kt0..2): pinned by "a"-constrained MFMA uses
  v8bf wreg[3][8];
  #pragma unroll
  for (int kt = 0; kt < 3; ++kt)
    #pragma unroll
    for (int ct = 0; ct < 8; ++ct)
      wreg[kt][ct] = *(const v8bf*)(wpack + ((kt*8 + w)*8 + ct)*512 + lane*8);

  // LDS-resident W (kt3,4)
  {
    const uint4* src = (const uint4*)(wpack + 3*SLABE);
    uint4* dst = (uint4*)lW;
    for (int i = tid; i < (2*SLABE)/8; i += 512) dst[i] = src[i];
  }
  float biasr[8];
  #pragma unroll
  for (int ct = 0; ct < 8; ++ct)
    biasr[ct] = bias[(ct >> 1)*256 + w*32 + (ct & 1)*16 + l15];

  { // zero both A buffers (h(-1)=0)
    unsigned* z = (unsigned*)lA;
    for (int i = tid; i < (2*16*AROWB)/4; i += 512) z[i] = 0;
  }
  __syncthreads();
  { // stage y[t=0] into buf0 (swizzled)
    unsigned v = 0;
    if (n0 + yrow < NSEQ)
      v = *(const unsigned*)(ybuf + ((size_t)(n0 + yrow)*TT + 0)*64 + ypair*2);
    *(unsigned*)(lA + a_off(yrow, 512 + ypair*4)) = v;
  }
  f32x4 creg[2];
  creg[0] = (f32x4){0.f,0.f,0.f,0.f};
  creg[1] = (f32x4){0.f,0.f,0.f,0.f};
  __syncthreads();

  const u16* wp = wpack;           // opaque-refreshed each step (defeats LICM)

  for (int t = 0; t < TT; ++t){
    char* Acur = lA + (t & 1)*16*AROWB;
    char* Anxt = lA + ((t + 1) & 1)*16*AROWB;

    asm("" : "+s"(wp));            // compiler may not hoist loads through this
    const u16* wpw = wp + w*4096 + lane*8;

    // issue stream kt5, kt6 (2-deep, into AGPR via "a" uses)
    v8bf sA[8], sB[8];
    #pragma unroll
    for (int ct = 0; ct < 8; ++ct) sA[ct] = *(const v8bf*)(wpw + 5*SLABE + ct*512);
    #pragma unroll
    for (int ct = 0; ct < 8; ++ct) sB[ct] = *(const v8bf*)(wpw + 6*SLABE + ct*512);

    // y prefetch for t+1
    unsigned yv = 0;
    if (t + 1 < TT && n0 + yrow < NSEQ)
      yv = *(const unsigned*)(ybuf + ((size_t)(n0 + yrow)*TT + (t + 1))*64 + ypair*2);

    // h(t-1) writeout (overlaps MFMA)
    if (t >= 1 && n0 + rrow < NSEQ){
      uint4 hv = *(const uint4*)(Acur + a_off(rrow, rchunk*16));
      *(uint4*)(hbuf + ((size_t)(n0 + rrow)*TT + (t - 1))*HH + rchunk*8) = hv;
    }

    f32x4 acc[8];
    #pragma unroll
    for (int ct = 0; ct < 8; ++ct)
      acc[ct] = (f32x4){biasr[ct], biasr[ct], biasr[ct], biasr[ct]};
    asm volatile("s_nop 1"
      : "+v"(acc[0]), "+v"(acc[1]), "+v"(acc[2]), "+v"(acc[3]),
        "+v"(acc[4]), "+v"(acc[5]), "+v"(acc[6]), "+v"(acc[7]));

    #define AFRAG(kt) (*(const v8bf*)(Acur + a_off(l15, (kt)*64 + q*16)))
    #define LFRAG(kt,ct) (*(const v8bf*)(lW + (((kt)-3)*8 + w)*4096 + (ct)*512 + lane*8))

    { v8bf a = AFRAG(0);  // kt0 (AGPR)
      #pragma unroll
      for (int ct = 0; ct < 8; ++ct) mfma_a(acc[ct], a, wreg[0][ct]); }
    { v8bf a = AFRAG(3);  // kt3 (LDS)
      #pragma unroll
      for (int ct = 0; ct < 8; ++ct) mfma_v(acc[ct], a, LFRAG(3,ct)); }
    { v8bf a = AFRAG(5);  // kt5 (stream A), refill A <- kt7
      #pragma unroll
      for (int ct = 0; ct < 8; ++ct) mfma_a(acc[ct], a, sA[ct]);
      #pragma unroll
      for (int ct = 0; ct < 8; ++ct) sA[ct] = *(const v8bf*)(wpw + 7*SLABE + ct*512); }
    { v8bf a = AFRAG(1);  // kt1 (AGPR)
      #pragma unroll
      for (int ct = 0; ct < 8; ++ct) mfma_a(acc[ct], a, wreg[1][ct]); }
    { v8bf a = AFRAG(4);  // kt4 (LDS)
      #pragma unroll
      for (int ct = 0; ct < 8; ++ct) mfma_v(acc[ct], a, LFRAG(4,ct)); }
    { v8bf a = AFRAG(6);  // kt6 (stream B), refill B <- kt8
      #pragma unroll
      for (int ct = 0; ct < 8; ++ct) mfma_a(acc[ct], a, sB[ct]);
      #pragma unroll
      for (int ct = 0; ct < 8; ++ct) sB[ct] = *(const v8bf*)(wpw + 8*SLABE + ct*512); }
    { v8bf a = AFRAG(2);  // kt2 (AGPR)
      #pragma unroll
      for (int ct = 0; ct < 8; ++ct) mfma_a(acc[ct], a, wreg[2][ct]); }
    { v8bf a = AFRAG(7);  // kt7 (stream A), refill A <- kt9
      #pragma unroll
      for (int ct = 0; ct < 8; ++ct) mfma_a(acc[ct], a, sA[ct]);
      #pragma unroll
      for (int ct = 0; ct < 8; ++ct) sA[ct] = *(const v8bf*)(wpw + 9*SLABE + ct*512); }
    { v8bf a = AFRAG(8);  // kt8 (stream B)
      #pragma unroll
      for (int ct = 0; ct < 8; ++ct) mfma_a(acc[ct], a, sB[ct]); }
    { v8bf a = AFRAG(9);  // kt9 (stream A)
      #pragma unroll
      for (int ct = 0; ct < 8; ++ct) mfma_a(acc[ct], a, sA[ct]); }

    // MFMA->VALU hazard guard (asm MFMAs are opaque to the hazard recognizer)
    asm volatile("s_nop 7\n\ts_nop 7\n\ts_nop 7"
      : "+v"(acc[0]), "+v"(acc[1]), "+v"(acc[2]), "+v"(acc[3]),
        "+v"(acc[4]), "+v"(acc[5]), "+v"(acc[6]), "+v"(acc[7]));

    // elementwise cell update: lane owns units w*32+u*16+l15, seqs 4q+j
    #pragma unroll
    for (int u = 0; u < 2; ++u){
      #pragma unroll
      for (int j = 0; j < 4; ++j){
        float xi = acc[0 + u][j], xf = acc[2 + u][j], xg = acc[4 + u][j], xo = acc[6 + u][j];
        float cv = sigm(xf)*creg[u][j] + sigm(xi)*tanh_f(xg);
        float hv = sigm(xo)*tanh_f(cv);
        creg[u][j] = cv;
        int row = 4*q + j, unit = w*32 + u*16 + l15;
        *(u16*)(Anxt + a_off(row, unit*2)) = f2bf(hv);
      }
    }
    // stage y[t+1]
    if (t + 1 < TT)
      *(unsigned*)(Anxt + a_off(yrow, 512 + ypair*4)) = yv;
    __syncthreads();
  }
  { // final h[255] sits in buf (TT&1)=0
    char* Afin = lA + (TT & 1)*16*AROWB;
    if (n0 + rrow < NSEQ){
      uint4 hv = *(const uint4*)(Afin + a_off(rrow, rchunk*16));
      *(uint4*)(hbuf + ((size_t)(n0 + rrow)*TT + (TT - 1))*HH + rchunk*8) = hv;
    }
  }
}

// ---- out = h @ W_lin^T + b_lin, written as (B,OUT,F,T)
__global__ __launch_bounds__(256) void k_outproj(const u16* __restrict__ hbuf,
      const u16* __restrict__ wlin, const float* __restrict__ blin,
      float* __restrict__ out){
  extern __shared__ char smem[];
  u16* sA = (u16*)smem;                 // [128][264] rows = t
  u16* sB = (u16*)(smem + 128*264*2);   // [64][264]  rows = o
  const int n = blockIdx.x, th = blockIdx.y, t0 = th*128;
  const int b = n / 257, f = n % 257;
  const int tid = threadIdx.x, lane = tid & 63, wv = tid >> 6;

  for (int i = tid; i < 128*32; i += 256){
    int r = i >> 5, part = i & 31;
    *(uint4*)(sA + r*264 + part*8) =
        *(const uint4*)(hbuf + ((size_t)n*TT + t0 + r)*HH + part*8);
  }
  for (int i = tid; i < (64*264)/2; i += 256)
    ((unsigned*)sB)[i] = ((const unsigned*)wlin)[i];
  __syncthreads();

  f32x4 acc[2][4];
  #pragma unroll
  for (int m = 0; m < 2; ++m)
    #pragma unroll
    for (int nt = 0; nt < 4; ++nt){
      float bv = blin[nt*16 + (lane & 15)];
      acc[m][nt] = (f32x4){bv, bv, bv, bv};
    }
  const int khi = (lane >> 4) * 8;
  #pragma unroll
  for (int kt = 0; kt < 8; ++kt){
    v8bf av[2];
    #pragma unroll
    for (int m = 0; m < 2; ++m){
      int mt = wv*2 + m;
      av[m] = *(const v8bf*)(sA + (mt*16 + (lane & 15))*264 + kt*32 + khi);
    }
    #pragma unroll
    for (int nt = 0; nt < 4; ++nt){
      v8bf bv = *(const v8bf*)(sB + (nt*16 + (lane & 15))*264 + kt*32 + khi);
      #pragma unroll
      for (int m = 0; m < 2; ++m)
        acc[m][nt] = __builtin_amdgcn_mfma_f32_16x16x32_bf16(av[m], bv, acc[m][nt], 0, 0, 0);
    }
  }
  #pragma unroll
  for (int m = 0; m < 2; ++m){
    int mt = wv*2 + m;
    #pragma unroll
    for (int nt = 0; nt < 4; ++nt){
      int o = nt*16 + (lane & 15);
      int tb = t0 + mt*16 + 4*(lane >> 4);
      *(f32x4*)(out + (((size_t)b*64 + o)*257 + f)*TT + tb) = acc[m][nt];
    }
  }
}

extern "C" void kernel_launch(void* const* d_in, const int* in_sizes, int n_in,
                              void* d_out, int out_size, void* d_ws, size_t ws_size,
                              hipStream_t stream) {
  const float* x   = (const float*)d_in[0];
  const float* Wih = (const float*)d_in[1];
  const float* Whh = (const float*)d_in[2];
  const float* bih = (const float*)d_in[3];
  const float* bhh = (const float*)d_in[4];
  const float* Wl  = (const float*)d_in[5];
  const float* bl  = (const float*)d_in[6];
  float* out = (float*)d_out;

  char* p = (char*)d_ws;
  u16*   wpack = (u16*)p;   p += 655360;                 // 10 slabs
  float* bias  = (float*)p; p += 4096;
  u16*   wlin  = (u16*)p;   p += 33792;
  u16*   ybuf  = (u16*)p;   p += (size_t)NSEQ*TT*CC*2;   // 33.7 MB
  u16*   hbuf  = (u16*)p;                                // 134.7 MB

  hipFuncSetAttribute((const void*)k_lstm,    hipFuncAttributeMaxDynamicSharedMemorySize, LSTM_LDS);
  hipFuncSetAttribute((const void*)k_outproj, hipFuncAttributeMaxDynamicSharedMemorySize, OUTP_LDS);

  k_pack_w <<<1280, 256, 0, stream>>>(Whh, Wih, wpack);
  k_bias   <<<4,    256, 0, stream>>>(bih, bhh, bias);
  k_wlin   <<<66,   256, 0, stream>>>(Wl, wlin);
  k_ytrans <<<1028, 256, 0, stream>>>(x, ybuf);
  k_lstm   <<<65, 512, LSTM_LDS, stream>>>(wpack, bias, ybuf, hbuf);
  k_outproj<<<dim3(1028, 2), 256, OUTP_LDS, stream>>>(hbuf, wlin, bl, out);
}